// Round 23
// baseline (154.889 us; speedup 1.0000x reference)
//
#include <hip/hip_runtime.h>
#include <hip/hip_bf16.h>
#include <stdint.h>

typedef __attribute__((ext_vector_type(8)))  __bf16 bf16x8;
typedef __attribute__((ext_vector_type(4)))  float  f32x4;
typedef __attribute__((ext_vector_type(16))) float  f32x16;
typedef __hip_bfloat16 bf16_t;

#define T_SEQ 2048
#define D_MODEL 1024
#define N_HEADS 16
#define N_KV 4
#define HD 64
#define LDQKV 1536
#define KDIM 1024

// Convert 16 consecutive fp32 (4x float4) -> 16 bf16 (2x int4)
__device__ inline void cvt16(const float4* __restrict__ g, int4* __restrict__ s) {
  float4 v0 = g[0], v1 = g[1], v2 = g[2], v3 = g[3];
  union { int4 i[2]; __hip_bfloat162 h[8]; } u;
  u.h[0] = __float22bfloat162_rn(make_float2(v0.x, v0.y));
  u.h[1] = __float22bfloat162_rn(make_float2(v0.z, v0.w));
  u.h[2] = __float22bfloat162_rn(make_float2(v1.x, v1.y));
  u.h[3] = __float22bfloat162_rn(make_float2(v1.z, v1.w));
  u.h[4] = __float22bfloat162_rn(make_float2(v2.x, v2.y));
  u.h[5] = __float22bfloat162_rn(make_float2(v2.z, v2.w));
  u.h[6] = __float22bfloat162_rn(make_float2(v3.x, v3.y));
  u.h[7] = __float22bfloat162_rn(make_float2(v3.z, v3.w));
  s[0] = u.i[0]; s[1] = u.i[1];
}

__device__ inline void storeC(bf16_t* p, float v) { *p = __float2bfloat16(v); }
__device__ inline void storeC(float* p, float v) { *p = v; }

// v_permlane32_swap_b32 vdst, vsrc: after plswap(a,b): a={a_L,b_L}, b={a_U,b_U}
__device__ inline void plswap(unsigned& a, unsigned& b) {
  asm volatile("v_permlane32_swap_b32 %0, %1" : "+v"(a), "+v"(b));
}

// HW transcendental exp2 (input already in log2 domain)
__device__ inline float fexp2(float x) {
  float r; asm("v_exp_f32 %0, %1" : "=v"(r) : "v"(x)); return r;
}
// HW packed fp32->bf16 (T12 recipe; no builtin on gfx950)
__device__ inline unsigned cvtpk(float lo, float hi) {
  unsigned r; asm("v_cvt_pk_bf16_f32 %0, %1, %2" : "=v"(r) : "v"(lo), "v"(hi));
  return r;
}

// async global->LDS, 16B per lane; lds dest must be wave-uniform base.
__device__ inline void gll16(const bf16_t* g, bf16_t* l) {
  __builtin_amdgcn_global_load_lds(
      (const __attribute__((address_space(1))) void*)g,
      (__attribute__((address_space(3))) void*)l, 16, 0, 0);
}

// ---------------------------------------------------------------------------
// fp32 -> bf16 bulk convert, x + all weights in ONE launch (units of 16 elem)
// ---------------------------------------------------------------------------
__global__ __launch_bounds__(256) void all_cvt(
    const float* __restrict__ x,
    const float* __restrict__ Wq, const float* __restrict__ Wk,
    const float* __restrict__ Wv, const float* __restrict__ Wo,
    bf16_t* __restrict__ xb, bf16_t* __restrict__ wqkvb,
    bf16_t* __restrict__ wob) {
  const int i = blockIdx.x * 256 + threadIdx.x;
  const float* s; bf16_t* d; int off;
  if (i < 524288)      { s = x;  d = xb;                   off = i; }
  else if (i < 589824) { s = Wq; d = wqkvb;                off = i - 524288; }
  else if (i < 606208) { s = Wk; d = wqkvb + 1024 * 1024;  off = i - 589824; }
  else if (i < 622592) { s = Wv; d = wqkvb + 1280 * 1024;  off = i - 606208; }
  else                 { s = Wo; d = wob;                  off = i - 622592; }
  cvt16((const float4*)s + off * 4, (int4*)d + off * 2);
}

// ---------------------------------------------------------------------------
// Plain GEMM bf16 x bf16, m97 structure, XCD panel clustering (id&7 =
// m_panel&7). No fused epilogue — r22 showed the fused RMS/RoPE/V-transpose
// tail cost ~35us (scattered cos/sin loads + strided 2B stores, serial
// after a short 32-iter K-loop). Separate proven kernels handle those.
// ---------------------------------------------------------------------------
template <int NX, typename CT>
__global__ __launch_bounds__(256) void gemm_bb(
    const bf16_t* __restrict__ A, const bf16_t* __restrict__ W,
    CT* __restrict__ C, const int ldC)
{
  __shared__ bf16_t As[128 * 32];
  __shared__ bf16_t Bs[128 * 32];
  const int tid = threadIdx.x;
  const int lane = tid & 63;
  const int wv = tid >> 6;
  const int wr = wv >> 1, wc = wv & 1;
  const int id  = (int)blockIdx.x;
  const int xcd = id & 7;
  const int seq = id >> 3;
  const int mp  = (seq / NX) * 8 + xcd;
  const int nt  = seq - (seq / NX) * NX;
  const int m0 = mp * 128;
  const int n0 = nt * 128;

  const int srow = lane >> 2;
  const int scol = (lane & 3) * 8;
  const bf16_t* gA = A + (size_t)(m0 + 32 * wv + srow) * KDIM + scol;
  const bf16_t* gB = W + (size_t)(n0 + 32 * wv + srow) * KDIM + scol;
  bf16_t* lA = As + wv * 1024;
  bf16_t* lB = Bs + wv * 1024;

  f32x4 acc[4][4];
#pragma unroll
  for (int m = 0; m < 4; ++m)
#pragma unroll
    for (int n = 0; n < 4; ++n)
      acc[m][n] = {0.f, 0.f, 0.f, 0.f};

  const int fr = lane & 15;
  const int fq = lane >> 4;

  for (int k0 = 0; k0 < KDIM; k0 += 32) {
    gll16(gA + k0, lA);
    gll16(gA + 16 * KDIM + k0, lA + 512);
    gll16(gB + k0, lB);
    gll16(gB + 16 * KDIM + k0, lB + 512);
    __syncthreads();
    bf16x8 af[4], bfv[4];
#pragma unroll
    for (int m = 0; m < 4; ++m)
      af[m] = *(const bf16x8*)(&As[(wr * 64 + m * 16 + fr) * 32 + fq * 8]);
#pragma unroll
    for (int n = 0; n < 4; ++n)
      bfv[n] = *(const bf16x8*)(&Bs[(wc * 64 + n * 16 + fr) * 32 + fq * 8]);
#pragma unroll
    for (int m = 0; m < 4; ++m)
#pragma unroll
      for (int n = 0; n < 4; ++n)
        acc[m][n] = __builtin_amdgcn_mfma_f32_16x16x32_bf16(af[m], bfv[n],
                                                            acc[m][n], 0, 0, 0);
    __syncthreads();
  }

#pragma unroll
  for (int m = 0; m < 4; ++m)
#pragma unroll
    for (int n = 0; n < 4; ++n)
#pragma unroll
      for (int r = 0; r < 4; ++r) {
        const int row = wr * 64 + m * 16 + fq * 4 + r;
        const int col = wc * 64 + n * 16 + fr;
        storeC(&C[(size_t)(m0 + row) * ldC + n0 + col], acc[m][n][r]);
      }
}

// ---------------------------------------------------------------------------
// RMSNorm + RoPE (r13-proven, verbatim): one block per (b,t) row; wave
// handles one head per iteration (lane = dim). Coalesced loads/stores.
// ---------------------------------------------------------------------------
__global__ __launch_bounds__(256) void rms_rope(
    bf16_t* __restrict__ qkv, const float* __restrict__ cosb,
    const float* __restrict__ sinb, const float* __restrict__ qs,
    const float* __restrict__ ks)
{
  const int row = blockIdx.x;
  const int t = row & (T_SEQ - 1);
  const int tid = threadIdx.x;
  const int lane = tid & 63;
  const int wv = tid >> 6;
  const int f = lane & 15;
  const float c = (lane < 32) ? cosb[t * 16 + f] : 0.f;
  const float s = (lane < 32) ? sinb[t * 16 + f] : 0.f;
  for (int hh = wv; hh < 20; hh += 4) {
    const size_t idx = (size_t)row * LDQKV + hh * 64 + lane;
    const float v = __bfloat162float(qkv[idx]);
    float ssum = v * v;
#pragma unroll
    for (int off = 32; off; off >>= 1) ssum += __shfl_xor(ssum, off);
    const float norm = rsqrtf(ssum * (1.f / 64.f) + 1e-6f);
    const float scale = (hh < 16 ? qs : ks)[lane];
    float val = v * norm * scale;
    const float partner = __shfl_xor(val, 16);
    if (lane < 16)      val = val * c - partner * s;
    else if (lane < 32) val = partner * s + val * c;
    qkv[idx] = __float2bfloat16(val);
  }
}

// ---------------------------------------------------------------------------
// V transpose (r13-proven, verbatim)
// ---------------------------------------------------------------------------
__global__ __launch_bounds__(256) void v_transpose(
    const bf16_t* __restrict__ qkv, bf16_t* __restrict__ v_t)
{
  __shared__ bf16_t tile[64 * 72];
  const int g = blockIdx.x;
  const int t0 = blockIdx.y * 64;
  const int tid = threadIdx.x;
  const int i = tid >> 2;
  const int dc = (tid & 3) * 16;
  const bf16_t* src = qkv + (size_t)((g >> 2) * T_SEQ + t0 + i) * LDQKV
                      + 1280 + (g & 3) * HD + dc;
  const int4* gs = (const int4*)src;
  int4 x0 = gs[0], x1 = gs[1];
  int4* st = (int4*)(&tile[i * 72 + dc]);
  st[0] = x0; st[1] = x1;
  __syncthreads();
  union { int4 v[2]; bf16_t h[16]; } u;
#pragma unroll
  for (int j = 0; j < 16; ++j) u.h[j] = tile[(dc + j) * 72 + i];
  int4* dst = (int4*)(v_t + (size_t)(g * HD + i) * T_SEQ + t0 + dc);
  dst[0] = u.v[0]; dst[1] = u.v[1];
}

// ---------------------------------------------------------------------------
// Causal GQA flash attention v16 (unchanged from r21 — passing): unpaired
// strips, quad blocks, split-k-2, balanced permutation, grid 1024.
// ---------------------------------------------------------------------------
__global__ __launch_bounds__(512) void attn(
    const bf16_t* __restrict__ qkv, const bf16_t* __restrict__ v_t,
    bf16_t* __restrict__ y)
{
  __shared__ int4 lds[2048];      // 32 KB: dbuf x (K 8KB + V 8KB)
  const int tid  = threadIdx.x;   // 0..511
  const int lane = tid & 63;
  const int w    = tid >> 6;      // 0..7
  const int spair= w >> 1;        // 0..3: strip within quad
  const int h    = w & 1;         // split-k parity
  const int ql   = lane & 31;
  const int hi   = lane >> 5;
  const int id   = (int)blockIdx.x;          // 0..1023
  const int low3 = id & 7;
  const int rest = id >> 3;                  // 0..127
  const int gsel = rest & 1;
  const int hh   = (rest >> 1) & 3;
  const int sbi  = rest >> 3;                // 0..15: quad index (pre-perm)
  const int sb   = ((sbi >> 2) & 1) ? (sbi + 4 - ((sbi >> 3) << 4)) : (15 - sbi);
  const int g16  = low3 + 8 * gsel;          // b*4+kvh (same-XCD clustering)
  const int b    = g16 >> 2, kvh = g16 & 3;
  const int hd   = kvh * 4 + hh;
  const int s    = 4 * sb + spair;           // this wave's single strip
  const int q_glob = s * 32 + ql;
  const int nt   = s + 1;                    // strip's 32-k tiles
  const int nR   = 2 * sb + 2;               // block-uniform 64-k rounds
  const float SCALE_LOG2 = 0.125f * 1.44269504089f;

  const int sid = tid & 255;
  const int u   = tid >> 8;
  const int kr = sid >> 3, kslot = sid & 7;
  const int vd = sid >> 2, vslot = sid & 3;
  const bf16_t* gK = qkv + (size_t)(b * T_SEQ + kr + u * 32) * LDQKV + 1024 + kvh * HD + kslot * 8;
  const bf16_t* gV = v_t + (size_t)((b * N_KV + kvh) * HD + vd) * T_SEQ + vslot * 8 + u * 32;
  const int wKidx = u * 256 + kr * 8 + (kslot ^ (kr & 7));
  const int wVidx = 512 + u * 256 + vd * 4 + (vslot ^ ((vd >> 1) & 3));

  int kridx[4];
#pragma unroll
  for (int c = 0; c < 4; ++c)
    kridx[c] = ql * 8 + ((2 * c + hi) ^ (ql & 7));
  const int vsw = (ql >> 1) & 3;
  const int v0idx = 512 + ql * 4 + (hi ^ vsw);
  const int v1idx = 512 + ql * 4 + ((2 + hi) ^ vsw);
  const int v2idx = 512 + (ql + 32) * 4 + (hi ^ vsw);
  const int v3idx = 512 + (ql + 32) * 4 + ((2 + hi) ^ vsw);

  union ob { unsigned uu[4]; bf16x8 v; } onesf;
#pragma unroll
  for (int i = 0; i < 4; ++i) onesf.uu[i] = 0x3F803F80u;

  f32x16 zro;
#pragma unroll
  for (int i = 0; i < 16; ++i) zro[i] = 0.f;

  float* lf = (float*)lds;

  const bf16_t* Qrow = qkv + (size_t)(b * T_SEQ + q_glob) * LDQKV + hd * HD + hi * 8;
  bf16x8 qfrag[4];
#pragma unroll
  for (int c = 0; c < 4; ++c) {
    bf16x8 raw = *(const bf16x8*)(Qrow + c * 16);
    bf16x8 sc;
#pragma unroll
    for (int j = 0; j < 8; ++j)
      sc[j] = (__bf16)((float)raw[j] * SCALE_LOG2);
    qfrag[c] = sc;
  }

  f32x16 acc0, acc1, accL;
#pragma unroll
  for (int i = 0; i < 16; ++i) { acc0[i] = 0.f; acc1[i] = 0.f; accL[i] = 0.f; }
  float m_run = -1e30f;

  {
    int4 kA = *(const int4*)gK;
    int4 vA = *(const int4*)gV;
    lds[wKidx] = kA;
    lds[wVidx] = vA;
  }
  __syncthreads();

  int buf = 0;
  for (int r = 0; r < nR; ++r) {
    int4 kA, vA;
    const bool more = (r + 1 < nR);
    if (more) {
      kA = *(const int4*)(gK + (size_t)(r + 1) * 64 * LDQKV);
      vA = *(const int4*)(gV + (r + 1) * 64);
    }

    const int t = 2 * r + h;     // this wave's tile (parity split)
    if (t < nt) {
      const int k0 = t << 5;
      const bool masked = (t == nt - 1);
      const int base = buf * 1024 + h * 256;

      bf16x8 kf0 = *(const bf16x8*)&lds[base + kridx[0]];
      bf16x8 kf1 = *(const bf16x8*)&lds[base + kridx[1]];
      bf16x8 kf2 = *(const bf16x8*)&lds[base + kridx[2]];
      bf16x8 kf3 = *(const bf16x8*)&lds[base + kridx[3]];

      __builtin_amdgcn_s_setprio(1);
      f32x16 st = __builtin_amdgcn_mfma_f32_32x32x16_bf16(kf0, qfrag[0], zro, 0, 0, 0);
      st = __builtin_amdgcn_mfma_f32_32x32x16_bf16(kf1, qfrag[1], st, 0, 0, 0);
      st = __builtin_amdgcn_mfma_f32_32x32x16_bf16(kf2, qfrag[2], st, 0, 0, 0);
      st = __builtin_amdgcn_mfma_f32_32x32x16_bf16(kf3, qfrag[3], st, 0, 0, 0);
      __builtin_amdgcn_s_setprio(0);

      if (masked) {
#pragma unroll
        for (int rr = 0; rr < 16; ++rr) {
          const int kg = k0 + (rr & 3) + 8 * (rr >> 2) + 4 * hi;
          if (kg > q_glob) st[rr] = -1e30f;
        }
      }
      float m01 = fmaxf(fmaxf(st[0], st[1]), st[2]);
      float m02 = fmaxf(fmaxf(st[3], st[4]), st[5]);
      float m03 = fmaxf(fmaxf(st[6], st[7]), st[8]);
      float m04 = fmaxf(fmaxf(st[9], st[10]), st[11]);
      float m05 = fmaxf(fmaxf(st[12], st[13]), st[14]);
      float m06 = fmaxf(fmaxf(m01, m02), m03);
      float m07 = fmaxf(fmaxf(m04, m05), st[15]);
      const float bmax = fmaxf(m06, m07);
      if (__any(bmax > m_run + 8.f)) {        // T13 defer-max
        const float rmax = fmaxf(bmax, __shfl_xor(bmax, 32));
        const float mnew = fmaxf(m_run, rmax);
        const float corr = fexp2(m_run - mnew);
#pragma unroll
        for (int i = 0; i < 16; ++i) { acc0[i] *= corr; acc1[i] *= corr; }
        accL[0] *= corr;
        m_run = mnew;
      }
      float pp[16];
#pragma unroll
      for (int rr = 0; rr < 16; ++rr) pp[rr] = fexp2(st[rr] - m_run);

      unsigned wp[8];
#pragma unroll
      for (int i = 0; i < 8; ++i) wp[i] = cvtpk(pp[2 * i], pp[2 * i + 1]);
      plswap(wp[0], wp[2]); plswap(wp[1], wp[3]);
      plswap(wp[4], wp[6]); plswap(wp[5], wp[7]);
      union fu { unsigned uu2[4]; bf16x8 v; };
      fu f1, f2;
      f1.uu2[0] = wp[0]; f1.uu2[1] = wp[1]; f1.uu2[2] = wp[2]; f1.uu2[3] = wp[3];
      f2.uu2[0] = wp[4]; f2.uu2[1] = wp[5]; f2.uu2[2] = wp[6]; f2.uu2[3] = wp[7];

      bf16x8 vf0 = *(const bf16x8*)&lds[base + v0idx];
      bf16x8 vf1 = *(const bf16x8*)&lds[base + v1idx];
      bf16x8 vf2 = *(const bf16x8*)&lds[base + v2idx];
      bf16x8 vf3 = *(const bf16x8*)&lds[base + v3idx];

      __builtin_amdgcn_s_setprio(1);
      acc0 = __builtin_amdgcn_mfma_f32_32x32x16_bf16(vf0, f1.v, acc0, 0, 0, 0);
      acc0 = __builtin_amdgcn_mfma_f32_32x32x16_bf16(vf1, f2.v, acc0, 0, 0, 0);
      acc1 = __builtin_amdgcn_mfma_f32_32x32x16_bf16(vf2, f1.v, acc1, 0, 0, 0);
      acc1 = __builtin_amdgcn_mfma_f32_32x32x16_bf16(vf3, f2.v, acc1, 0, 0, 0);
      accL = __builtin_amdgcn_mfma_f32_32x32x16_bf16(onesf.v, f1.v, accL, 0, 0, 0);
      accL = __builtin_amdgcn_mfma_f32_32x32x16_bf16(onesf.v, f2.v, accL, 0, 0, 0);
      __builtin_amdgcn_s_setprio(0);
    }

    if (more) {
      const int nb = (buf ^ 1) * 1024;
      lds[nb + wKidx] = kA;
      lds[nb + wVidx] = vA;
    }
    __syncthreads();
    buf ^= 1;
  }

  // ---- split-k merge: h=1 publishes partials, h=0 merges & stores ----
  float cA = 1.f, cB = 0.f, l_mrg = 0.f;
  if (h == 1) {
    const int fb = spair * 1216 + lane * 19;
#pragma unroll
    for (int i = 0; i < 16; ++i) lf[fb + i] = acc0[i];
    lf[fb + 16] = m_run;
    lf[fb + 17] = accL[0];
  }
  __syncthreads();
  if (h == 0) {
    const int fb = spair * 1216 + lane * 19;
    const float mB = lf[fb + 16], lB = lf[fb + 17];
    const float mM = fmaxf(m_run, mB);
    cA = fexp2(m_run - mM);
    cB = fexp2(mB - mM);
    l_mrg = accL[0] * cA + lB * cB;
#pragma unroll
    for (int i = 0; i < 16; ++i) acc0[i] = acc0[i] * cA + lf[fb + i] * cB;
  }
  __syncthreads();
  if (h == 1) {
    const int fb2 = spair * 1088 + lane * 17;
#pragma unroll
    for (int i = 0; i < 16; ++i) lf[fb2 + i] = acc1[i];
  }
  __syncthreads();
  if (h == 0) {
    const int fb2 = spair * 1088 + lane * 17;
#pragma unroll
    for (int i = 0; i < 16; ++i) acc1[i] = acc1[i] * cA + lf[fb2 + i] * cB;
    const float inv = 1.f / l_mrg;
    bf16_t* yrow = y + (size_t)(b * T_SEQ + q_glob) * D_MODEL + hd * HD;
#pragma unroll
    for (int gg = 0; gg < 4; ++gg) {
      uint2 o0, o1;
      o0.x = cvtpk(acc0[4 * gg + 0] * inv, acc0[4 * gg + 1] * inv);
      o0.y = cvtpk(acc0[4 * gg + 2] * inv, acc0[4 * gg + 3] * inv);
      o1.x = cvtpk(acc1[4 * gg + 0] * inv, acc1[4 * gg + 1] * inv);
      o1.y = cvtpk(acc1[4 * gg + 2] * inv, acc1[4 * gg + 3] * inv);
      *(uint2*)(yrow + 8 * gg + 4 * hi)      = o0;
      *(uint2*)(yrow + 32 + 8 * gg + 4 * hi) = o1;
    }
  }
}

// ---------------------------------------------------------------------------
extern "C" void kernel_launch(void* const* d_in, const int* in_sizes, int n_in,
                              void* d_out, int out_size, void* d_ws,
                              size_t ws_size, hipStream_t stream) {
  const float* x    = (const float*)d_in[0];
  const float* cosb = (const float*)d_in[1];
  const float* sinb = (const float*)d_in[2];
  const float* Wq   = (const float*)d_in[3];
  const float* Wk   = (const float*)d_in[4];
  const float* Wv   = (const float*)d_in[5];
  const float* Wo   = (const float*)d_in[6];
  const float* qs   = (const float*)d_in[7];
  const float* ks   = (const float*)d_in[8];
  float* out = (float*)d_out;   // reference output dtype is float32

  char* ws = (char*)d_ws;
  bf16_t* qkv   = (bf16_t*)ws;                       // 25165824 B
  bf16_t* v_t   = (bf16_t*)(ws + 25165824);          // 4194304 B
  bf16_t* y     = (bf16_t*)(ws + 29360128);          // 16777216 B (= xb alias)
  bf16_t* xb    = y;                                 // xb dead before attn writes y
  bf16_t* wqkvb = (bf16_t*)(ws + 46137344);          // 3145728 B
  bf16_t* wob   = (bf16_t*)(ws + 49283072);          // 2097152 B

  // 0. fp32 -> bf16 converts (one launch: x + all weights)
  all_cvt<<<dim3(2688), 256, 0, stream>>>(x, Wq, Wk, Wv, Wo, xb, wqkvb, wob);

  // 1. QKV projection (plain GEMM, XCD-clustered)
  gemm_bb<12, bf16_t><<<dim3(768), 256, 0, stream>>>(xb, wqkvb, qkv, LDQKV);
  // 2. RMSNorm + RoPE in-place on q,k (coalesced, proven)
  rms_rope<<<dim3(8192), 256, 0, stream>>>(qkv, cosb, sinb, qs, ks);
  // 3. V transpose (proven)
  v_transpose<<<dim3(16, 32), 256, 0, stream>>>(qkv, v_t);
  // 4. causal GQA flash attention -> y (unpaired quad blocks, grid 1024)
  attn<<<dim3(1024), 512, 0, stream>>>(qkv, v_t, y);
  // 5. output projection (plain GEMM, XCD-clustered)
  gemm_bb<8, float><<<dim3(512), 256, 0, stream>>>(y, wob, out, D_MODEL);
}

// Round 24
// 139.689 us; speedup vs baseline: 1.1088x; 1.1088x over previous
//
#include <hip/hip_runtime.h>
#include <hip/hip_bf16.h>
#include <stdint.h>

typedef __attribute__((ext_vector_type(8)))  __bf16 bf16x8;
typedef __attribute__((ext_vector_type(4)))  float  f32x4;
typedef __attribute__((ext_vector_type(16))) float  f32x16;
typedef __hip_bfloat16 bf16_t;

#define T_SEQ 2048
#define D_MODEL 1024
#define N_HEADS 16
#define N_KV 4
#define HD 64
#define LDQKV 1536
#define KDIM 1024

// Convert 16 consecutive fp32 (4x float4) -> 16 bf16 (2x int4)
__device__ inline void cvt16(const float4* __restrict__ g, int4* __restrict__ s) {
  float4 v0 = g[0], v1 = g[1], v2 = g[2], v3 = g[3];
  union { int4 i[2]; __hip_bfloat162 h[8]; } u;
  u.h[0] = __float22bfloat162_rn(make_float2(v0.x, v0.y));
  u.h[1] = __float22bfloat162_rn(make_float2(v0.z, v0.w));
  u.h[2] = __float22bfloat162_rn(make_float2(v1.x, v1.y));
  u.h[3] = __float22bfloat162_rn(make_float2(v1.z, v1.w));
  u.h[4] = __float22bfloat162_rn(make_float2(v2.x, v2.y));
  u.h[5] = __float22bfloat162_rn(make_float2(v2.z, v2.w));
  u.h[6] = __float22bfloat162_rn(make_float2(v3.x, v3.y));
  u.h[7] = __float22bfloat162_rn(make_float2(v3.z, v3.w));
  s[0] = u.i[0]; s[1] = u.i[1];
}

__device__ inline void storeC(bf16_t* p, float v) { *p = __float2bfloat16(v); }
__device__ inline void storeC(float* p, float v) { *p = v; }

// v_permlane32_swap_b32 vdst, vsrc: after plswap(a,b): a={a_L,b_L}, b={a_U,b_U}
__device__ inline void plswap(unsigned& a, unsigned& b) {
  asm volatile("v_permlane32_swap_b32 %0, %1" : "+v"(a), "+v"(b));
}

// HW transcendental exp2 (input already in log2 domain)
__device__ inline float fexp2(float x) {
  float r; asm("v_exp_f32 %0, %1" : "=v"(r) : "v"(x)); return r;
}
// HW packed fp32->bf16 (T12 recipe; no builtin on gfx950)
__device__ inline unsigned cvtpk(float lo, float hi) {
  unsigned r; asm("v_cvt_pk_bf16_f32 %0, %1, %2" : "=v"(r) : "v"(lo), "v"(hi));
  return r;
}

// async global->LDS, 16B per lane; lds dest must be wave-uniform base.
__device__ inline void gll16(const bf16_t* g, bf16_t* l) {
  __builtin_amdgcn_global_load_lds(
      (const __attribute__((address_space(1))) void*)g,
      (__attribute__((address_space(3))) void*)l, 16, 0, 0);
}

// ---------------------------------------------------------------------------
// fp32 -> bf16 bulk convert, x + all weights in ONE launch (units of 16 elem)
// ---------------------------------------------------------------------------
__global__ __launch_bounds__(256) void all_cvt(
    const float* __restrict__ x,
    const float* __restrict__ Wq, const float* __restrict__ Wk,
    const float* __restrict__ Wv, const float* __restrict__ Wo,
    bf16_t* __restrict__ xb, bf16_t* __restrict__ wqkvb,
    bf16_t* __restrict__ wob) {
  const int i = blockIdx.x * 256 + threadIdx.x;
  const float* s; bf16_t* d; int off;
  if (i < 524288)      { s = x;  d = xb;                   off = i; }
  else if (i < 589824) { s = Wq; d = wqkvb;                off = i - 524288; }
  else if (i < 606208) { s = Wk; d = wqkvb + 1024 * 1024;  off = i - 589824; }
  else if (i < 622592) { s = Wv; d = wqkvb + 1280 * 1024;  off = i - 606208; }
  else                 { s = Wo; d = wob;                  off = i - 622592; }
  cvt16((const float4*)s + off * 4, (int4*)d + off * 2);
}

// ---------------------------------------------------------------------------
// GEMM bf16 x bf16, r22 structure (XCD panel clustering, fused QKV epilogue)
// with BK=64: two independent linear [128][32] subtiles per operand per
// round -> 16 barrier rounds instead of 32, 32 MFMA per round. Staging
// pattern per subtile identical to the proven BK=32 code (2-way-free LDS).
// ---------------------------------------------------------------------------
template <int MODE, int NX, typename CT>
__global__ __launch_bounds__(256) void gemm_bb(
    const bf16_t* __restrict__ A, const bf16_t* __restrict__ W,
    CT* __restrict__ C, const int ldC,
    const float* __restrict__ cosb, const float* __restrict__ sinb,
    const float* __restrict__ qs, const float* __restrict__ ks,
    bf16_t* __restrict__ v_t)
{
  __shared__ bf16_t Smem[16384];        // 32 KB: As0|As1|Bs0|Bs1 (8KB each)
  bf16_t* As0 = Smem;
  bf16_t* As1 = Smem + 4096;
  bf16_t* Bs0 = Smem + 8192;
  bf16_t* Bs1 = Smem + 12288;
  const int tid = threadIdx.x;
  const int lane = tid & 63;
  const int wv = tid >> 6;
  const int wr = wv >> 1, wc = wv & 1;
  // XCD-clustered decode: id&7 == m_panel&7 under round-robin dispatch.
  const int id  = (int)blockIdx.x;
  const int xcd = id & 7;
  const int seq = id >> 3;
  const int mp  = (seq / NX) * 8 + xcd;
  const int nt  = seq - (seq / NX) * NX;
  const int m0 = mp * 128;
  const int n0 = nt * 128;

  const int srow = lane >> 2;
  const int scol = (lane & 3) * 8;
  const bf16_t* gA = A + (size_t)(m0 + 32 * wv + srow) * KDIM + scol;
  const bf16_t* gB = W + (size_t)(n0 + 32 * wv + srow) * KDIM + scol;
  bf16_t* lA0 = As0 + wv * 1024;
  bf16_t* lA1 = As1 + wv * 1024;
  bf16_t* lB0 = Bs0 + wv * 1024;
  bf16_t* lB1 = Bs1 + wv * 1024;

  f32x4 acc[4][4];
#pragma unroll
  for (int m = 0; m < 4; ++m)
#pragma unroll
    for (int n = 0; n < 4; ++n)
      acc[m][n] = {0.f, 0.f, 0.f, 0.f};

  const int fr = lane & 15;
  const int fq = lane >> 4;

  for (int k0 = 0; k0 < KDIM; k0 += 64) {
    gll16(gA + k0, lA0);
    gll16(gA + 16 * KDIM + k0, lA0 + 512);
    gll16(gB + k0, lB0);
    gll16(gB + 16 * KDIM + k0, lB0 + 512);
    gll16(gA + k0 + 32, lA1);
    gll16(gA + 16 * KDIM + k0 + 32, lA1 + 512);
    gll16(gB + k0 + 32, lB1);
    gll16(gB + 16 * KDIM + k0 + 32, lB1 + 512);
    __syncthreads();
    {
      bf16x8 af[4], bfv[4];
#pragma unroll
      for (int m = 0; m < 4; ++m)
        af[m] = *(const bf16x8*)(&As0[(wr * 64 + m * 16 + fr) * 32 + fq * 8]);
#pragma unroll
      for (int n = 0; n < 4; ++n)
        bfv[n] = *(const bf16x8*)(&Bs0[(wc * 64 + n * 16 + fr) * 32 + fq * 8]);
#pragma unroll
      for (int m = 0; m < 4; ++m)
#pragma unroll
        for (int n = 0; n < 4; ++n)
          acc[m][n] = __builtin_amdgcn_mfma_f32_16x16x32_bf16(af[m], bfv[n],
                                                              acc[m][n], 0, 0, 0);
    }
    {
      bf16x8 af[4], bfv[4];
#pragma unroll
      for (int m = 0; m < 4; ++m)
        af[m] = *(const bf16x8*)(&As1[(wr * 64 + m * 16 + fr) * 32 + fq * 8]);
#pragma unroll
      for (int n = 0; n < 4; ++n)
        bfv[n] = *(const bf16x8*)(&Bs1[(wc * 64 + n * 16 + fr) * 32 + fq * 8]);
#pragma unroll
      for (int m = 0; m < 4; ++m)
#pragma unroll
        for (int n = 0; n < 4; ++n)
          acc[m][n] = __builtin_amdgcn_mfma_f32_16x16x32_bf16(af[m], bfv[n],
                                                              acc[m][n], 0, 0, 0);
    }
    __syncthreads();
  }

  if (MODE == 0 || n0 < 1280) {
    if (MODE == 1) {
      const float* stab = (n0 < 1024) ? qs : ks;
      float sc0 = stab[fr], sc1 = stab[16 + fr], sc2 = stab[32 + fr], sc3 = stab[48 + fr];
#pragma unroll
      for (int m = 0; m < 4; ++m)
#pragma unroll
        for (int r = 0; r < 4; ++r) {
          const int row = m0 + wr * 64 + m * 16 + fq * 4 + r;
          const int t = row & (T_SEQ - 1);
          float ss = acc[m][0][r] * acc[m][0][r] + acc[m][1][r] * acc[m][1][r]
                   + acc[m][2][r] * acc[m][2][r] + acc[m][3][r] * acc[m][3][r];
          ss += __shfl_xor(ss, 1);
          ss += __shfl_xor(ss, 2);
          ss += __shfl_xor(ss, 4);
          ss += __shfl_xor(ss, 8);
          const float nrm = rsqrtf(ss * (1.f / 64.f) + 1e-6f);
          const float v0 = acc[m][0][r] * nrm * sc0;
          const float v1 = acc[m][1][r] * nrm * sc1;
          const float v2 = acc[m][2][r] * nrm * sc2;
          const float v3 = acc[m][3][r] * nrm * sc3;
          const float c = cosb[t * 16 + fr];
          const float s = sinb[t * 16 + fr];
          union { unsigned u; bf16_t hh[2]; } pa, pb;
          pa.u = cvtpk(v0 * c - v1 * s, v0 * s + v1 * c);
          pb.u = cvtpk(v2, v3);
          bf16_t* p = (bf16_t*)C + (size_t)row * ldC + n0 + wc * 64 + fr;
          p[0]  = pa.hh[0];
          p[16] = pa.hh[1];
          p[32] = pb.hh[0];
          p[48] = pb.hh[1];
        }
    } else {
#pragma unroll
      for (int m = 0; m < 4; ++m)
#pragma unroll
        for (int n = 0; n < 4; ++n)
#pragma unroll
          for (int r = 0; r < 4; ++r) {
            const int row = wr * 64 + m * 16 + fq * 4 + r;
            const int col = wc * 64 + n * 16 + fr;
            storeC(&C[(size_t)(m0 + row) * ldC + n0 + col], acc[m][n][r]);
          }
    }
  } else {
    // v blocks: coalesced transposed store via LDS (r22-proven). Uses the
    // first 16KB of Smem as a [64][128] bf16 tile with col XOR-swizzle.
    const int b4 = (m0 >> 11) * 4;
    const int t0base = m0 & (T_SEQ - 1);
    const int vcol = tid & 127;
    const int vc = n0 - 1280 + vcol;
    const int g = b4 + (vc >> 6);
    const int d = vc & 63;
#pragma unroll
    for (int half = 0; half < 2; ++half) {
      if (wr == half) {
#pragma unroll
        for (int m = 0; m < 4; ++m)
#pragma unroll
          for (int n = 0; n < 4; ++n)
#pragma unroll
            for (int r2 = 0; r2 < 4; r2 += 2) {
              union { unsigned u; bf16_t hh[2]; } pk2;
              pk2.u = cvtpk(acc[m][n][r2], acc[m][n][r2 + 1]);
              const int tl0 = m * 16 + fq * 4 + r2;
              const int col = wc * 64 + n * 16 + fr;
              const int sw = ((tl0 >> 2) & 7) << 4;   // same for tl0, tl0+1
              Smem[tl0 * 128 + (col ^ sw)]       = pk2.hh[0];
              Smem[(tl0 + 1) * 128 + (col ^ sw)] = pk2.hh[1];
            }
      }
      __syncthreads();
      bf16_t* dst0 = v_t + ((size_t)(g * HD + d)) * T_SEQ + t0base + half * 64;
#pragma unroll
      for (int ci = 0; ci < 2; ++ci) {
        const int cu = (tid >> 7) + ci * 2;           // chunk 0..3 (16 t each)
        union { int4 q[2]; bf16_t hh[16]; } ld;
#pragma unroll
        for (int t = 0; t < 16; ++t) {
          const int tt = cu * 16 + t;
          ld.hh[t] = Smem[tt * 128 + (vcol ^ (((tt >> 2) & 7) << 4))];
        }
        *(int4*)(dst0 + cu * 16)     = ld.q[0];
        *(int4*)(dst0 + cu * 16 + 8) = ld.q[1];
      }
      __syncthreads();
    }
  }
}

// ---------------------------------------------------------------------------
// Causal GQA flash attention v16 (unchanged from r21 — passing): unpaired
// strips, quad blocks, split-k-2, balanced permutation, grid 1024.
// ---------------------------------------------------------------------------
__global__ __launch_bounds__(512) void attn(
    const bf16_t* __restrict__ qkv, const bf16_t* __restrict__ v_t,
    bf16_t* __restrict__ y)
{
  __shared__ int4 lds[2048];      // 32 KB: dbuf x (K 8KB + V 8KB)
  const int tid  = threadIdx.x;   // 0..511
  const int lane = tid & 63;
  const int w    = tid >> 6;      // 0..7
  const int spair= w >> 1;        // 0..3: strip within quad
  const int h    = w & 1;         // split-k parity
  const int ql   = lane & 31;
  const int hi   = lane >> 5;
  const int id   = (int)blockIdx.x;          // 0..1023
  const int low3 = id & 7;
  const int rest = id >> 3;                  // 0..127
  const int gsel = rest & 1;
  const int hh   = (rest >> 1) & 3;
  const int sbi  = rest >> 3;                // 0..15: quad index (pre-perm)
  const int sb   = ((sbi >> 2) & 1) ? (sbi + 4 - ((sbi >> 3) << 4)) : (15 - sbi);
  const int g16  = low3 + 8 * gsel;          // b*4+kvh (same-XCD clustering)
  const int b    = g16 >> 2, kvh = g16 & 3;
  const int hd   = kvh * 4 + hh;
  const int s    = 4 * sb + spair;           // this wave's single strip
  const int q_glob = s * 32 + ql;
  const int nt   = s + 1;                    // strip's 32-k tiles
  const int nR   = 2 * sb + 2;               // block-uniform 64-k rounds
  const float SCALE_LOG2 = 0.125f * 1.44269504089f;

  const int sid = tid & 255;
  const int u   = tid >> 8;
  const int kr = sid >> 3, kslot = sid & 7;
  const int vd = sid >> 2, vslot = sid & 3;
  const bf16_t* gK = qkv + (size_t)(b * T_SEQ + kr + u * 32) * LDQKV + 1024 + kvh * HD + kslot * 8;
  const bf16_t* gV = v_t + (size_t)((b * N_KV + kvh) * HD + vd) * T_SEQ + vslot * 8 + u * 32;
  const int wKidx = u * 256 + kr * 8 + (kslot ^ (kr & 7));
  const int wVidx = 512 + u * 256 + vd * 4 + (vslot ^ ((vd >> 1) & 3));

  int kridx[4];
#pragma unroll
  for (int c = 0; c < 4; ++c)
    kridx[c] = ql * 8 + ((2 * c + hi) ^ (ql & 7));
  const int vsw = (ql >> 1) & 3;
  const int v0idx = 512 + ql * 4 + (hi ^ vsw);
  const int v1idx = 512 + ql * 4 + ((2 + hi) ^ vsw);
  const int v2idx = 512 + (ql + 32) * 4 + (hi ^ vsw);
  const int v3idx = 512 + (ql + 32) * 4 + ((2 + hi) ^ vsw);

  union ob { unsigned uu[4]; bf16x8 v; } onesf;
#pragma unroll
  for (int i = 0; i < 4; ++i) onesf.uu[i] = 0x3F803F80u;

  f32x16 zro;
#pragma unroll
  for (int i = 0; i < 16; ++i) zro[i] = 0.f;

  float* lf = (float*)lds;

  const bf16_t* Qrow = qkv + (size_t)(b * T_SEQ + q_glob) * LDQKV + hd * HD + hi * 8;
  bf16x8 qfrag[4];
#pragma unroll
  for (int c = 0; c < 4; ++c) {
    bf16x8 raw = *(const bf16x8*)(Qrow + c * 16);
    bf16x8 sc;
#pragma unroll
    for (int j = 0; j < 8; ++j)
      sc[j] = (__bf16)((float)raw[j] * SCALE_LOG2);
    qfrag[c] = sc;
  }

  f32x16 acc0, acc1, accL;
#pragma unroll
  for (int i = 0; i < 16; ++i) { acc0[i] = 0.f; acc1[i] = 0.f; accL[i] = 0.f; }
  float m_run = -1e30f;

  {
    int4 kA = *(const int4*)gK;
    int4 vA = *(const int4*)gV;
    lds[wKidx] = kA;
    lds[wVidx] = vA;
  }
  __syncthreads();

  int buf = 0;
  for (int r = 0; r < nR; ++r) {
    int4 kA, vA;
    const bool more = (r + 1 < nR);
    if (more) {
      kA = *(const int4*)(gK + (size_t)(r + 1) * 64 * LDQKV);
      vA = *(const int4*)(gV + (r + 1) * 64);
    }

    const int t = 2 * r + h;     // this wave's tile (parity split)
    if (t < nt) {
      const int k0 = t << 5;
      const bool masked = (t == nt - 1);
      const int base = buf * 1024 + h * 256;

      bf16x8 kf0 = *(const bf16x8*)&lds[base + kridx[0]];
      bf16x8 kf1 = *(const bf16x8*)&lds[base + kridx[1]];
      bf16x8 kf2 = *(const bf16x8*)&lds[base + kridx[2]];
      bf16x8 kf3 = *(const bf16x8*)&lds[base + kridx[3]];

      __builtin_amdgcn_s_setprio(1);
      f32x16 st = __builtin_amdgcn_mfma_f32_32x32x16_bf16(kf0, qfrag[0], zro, 0, 0, 0);
      st = __builtin_amdgcn_mfma_f32_32x32x16_bf16(kf1, qfrag[1], st, 0, 0, 0);
      st = __builtin_amdgcn_mfma_f32_32x32x16_bf16(kf2, qfrag[2], st, 0, 0, 0);
      st = __builtin_amdgcn_mfma_f32_32x32x16_bf16(kf3, qfrag[3], st, 0, 0, 0);
      __builtin_amdgcn_s_setprio(0);

      if (masked) {
#pragma unroll
        for (int rr = 0; rr < 16; ++rr) {
          const int kg = k0 + (rr & 3) + 8 * (rr >> 2) + 4 * hi;
          if (kg > q_glob) st[rr] = -1e30f;
        }
      }
      float m01 = fmaxf(fmaxf(st[0], st[1]), st[2]);
      float m02 = fmaxf(fmaxf(st[3], st[4]), st[5]);
      float m03 = fmaxf(fmaxf(st[6], st[7]), st[8]);
      float m04 = fmaxf(fmaxf(st[9], st[10]), st[11]);
      float m05 = fmaxf(fmaxf(st[12], st[13]), st[14]);
      float m06 = fmaxf(fmaxf(m01, m02), m03);
      float m07 = fmaxf(fmaxf(m04, m05), st[15]);
      const float bmax = fmaxf(m06, m07);
      if (__any(bmax > m_run + 8.f)) {        // T13 defer-max
        const float rmax = fmaxf(bmax, __shfl_xor(bmax, 32));
        const float mnew = fmaxf(m_run, rmax);
        const float corr = fexp2(m_run - mnew);
#pragma unroll
        for (int i = 0; i < 16; ++i) { acc0[i] *= corr; acc1[i] *= corr; }
        accL[0] *= corr;
        m_run = mnew;
      }
      float pp[16];
#pragma unroll
      for (int rr = 0; rr < 16; ++rr) pp[rr] = fexp2(st[rr] - m_run);

      unsigned wp[8];
#pragma unroll
      for (int i = 0; i < 8; ++i) wp[i] = cvtpk(pp[2 * i], pp[2 * i + 1]);
      plswap(wp[0], wp[2]); plswap(wp[1], wp[3]);
      plswap(wp[4], wp[6]); plswap(wp[5], wp[7]);
      union fu { unsigned uu2[4]; bf16x8 v; };
      fu f1, f2;
      f1.uu2[0] = wp[0]; f1.uu2[1] = wp[1]; f1.uu2[2] = wp[2]; f1.uu2[3] = wp[3];
      f2.uu2[0] = wp[4]; f2.uu2[1] = wp[5]; f2.uu2[2] = wp[6]; f2.uu2[3] = wp[7];

      bf16x8 vf0 = *(const bf16x8*)&lds[base + v0idx];
      bf16x8 vf1 = *(const bf16x8*)&lds[base + v1idx];
      bf16x8 vf2 = *(const bf16x8*)&lds[base + v2idx];
      bf16x8 vf3 = *(const bf16x8*)&lds[base + v3idx];

      __builtin_amdgcn_s_setprio(1);
      acc0 = __builtin_amdgcn_mfma_f32_32x32x16_bf16(vf0, f1.v, acc0, 0, 0, 0);
      acc0 = __builtin_amdgcn_mfma_f32_32x32x16_bf16(vf1, f2.v, acc0, 0, 0, 0);
      acc1 = __builtin_amdgcn_mfma_f32_32x32x16_bf16(vf2, f1.v, acc1, 0, 0, 0);
      acc1 = __builtin_amdgcn_mfma_f32_32x32x16_bf16(vf3, f2.v, acc1, 0, 0, 0);
      accL = __builtin_amdgcn_mfma_f32_32x32x16_bf16(onesf.v, f1.v, accL, 0, 0, 0);
      accL = __builtin_amdgcn_mfma_f32_32x32x16_bf16(onesf.v, f2.v, accL, 0, 0, 0);
      __builtin_amdgcn_s_setprio(0);
    }

    if (more) {
      const int nb = (buf ^ 1) * 1024;
      lds[nb + wKidx] = kA;
      lds[nb + wVidx] = vA;
    }
    __syncthreads();
    buf ^= 1;
  }

  // ---- split-k merge: h=1 publishes partials, h=0 merges & stores ----
  float cA = 1.f, cB = 0.f, l_mrg = 0.f;
  if (h == 1) {
    const int fb = spair * 1216 + lane * 19;
#pragma unroll
    for (int i = 0; i < 16; ++i) lf[fb + i] = acc0[i];
    lf[fb + 16] = m_run;
    lf[fb + 17] = accL[0];
  }
  __syncthreads();
  if (h == 0) {
    const int fb = spair * 1216 + lane * 19;
    const float mB = lf[fb + 16], lB = lf[fb + 17];
    const float mM = fmaxf(m_run, mB);
    cA = fexp2(m_run - mM);
    cB = fexp2(mB - mM);
    l_mrg = accL[0] * cA + lB * cB;
#pragma unroll
    for (int i = 0; i < 16; ++i) acc0[i] = acc0[i] * cA + lf[fb + i] * cB;
  }
  __syncthreads();
  if (h == 1) {
    const int fb2 = spair * 1088 + lane * 17;
#pragma unroll
    for (int i = 0; i < 16; ++i) lf[fb2 + i] = acc1[i];
  }
  __syncthreads();
  if (h == 0) {
    const int fb2 = spair * 1088 + lane * 17;
#pragma unroll
    for (int i = 0; i < 16; ++i) acc1[i] = acc1[i] * cA + lf[fb2 + i] * cB;
    const float inv = 1.f / l_mrg;
    bf16_t* yrow = y + (size_t)(b * T_SEQ + q_glob) * D_MODEL + hd * HD;
#pragma unroll
    for (int gg = 0; gg < 4; ++gg) {
      uint2 o0, o1;
      o0.x = cvtpk(acc0[4 * gg + 0] * inv, acc0[4 * gg + 1] * inv);
      o0.y = cvtpk(acc0[4 * gg + 2] * inv, acc0[4 * gg + 3] * inv);
      o1.x = cvtpk(acc1[4 * gg + 0] * inv, acc1[4 * gg + 1] * inv);
      o1.y = cvtpk(acc1[4 * gg + 2] * inv, acc1[4 * gg + 3] * inv);
      *(uint2*)(yrow + 8 * gg + 4 * hi)      = o0;
      *(uint2*)(yrow + 32 + 8 * gg + 4 * hi) = o1;
    }
  }
}

// ---------------------------------------------------------------------------
extern "C" void kernel_launch(void* const* d_in, const int* in_sizes, int n_in,
                              void* d_out, int out_size, void* d_ws,
                              size_t ws_size, hipStream_t stream) {
  const float* x    = (const float*)d_in[0];
  const float* cosb = (const float*)d_in[1];
  const float* sinb = (const float*)d_in[2];
  const float* Wq   = (const float*)d_in[3];
  const float* Wk   = (const float*)d_in[4];
  const float* Wv   = (const float*)d_in[5];
  const float* Wo   = (const float*)d_in[6];
  const float* qs   = (const float*)d_in[7];
  const float* ks   = (const float*)d_in[8];
  float* out = (float*)d_out;   // reference output dtype is float32

  char* ws = (char*)d_ws;
  bf16_t* qkv   = (bf16_t*)ws;                       // 25165824 B
  bf16_t* v_t   = (bf16_t*)(ws + 25165824);          // 4194304 B
  bf16_t* y     = (bf16_t*)(ws + 29360128);          // 16777216 B (= xb alias)
  bf16_t* xb    = y;                                 // xb dead before attn writes y
  bf16_t* wqkvb = (bf16_t*)(ws + 46137344);          // 3145728 B
  bf16_t* wob   = (bf16_t*)(ws + 49283072);          // 2097152 B

  // 0. fp32 -> bf16 converts (one launch: x + all weights)
  all_cvt<<<dim3(2688), 256, 0, stream>>>(x, Wq, Wk, Wv, Wo, xb, wqkvb, wob);

  // 1. fused QKV projection + RMSNorm + RoPE + V-transpose (XCD-clustered,
  //    BK=64)
  gemm_bb<1, 12, bf16_t><<<dim3(768), 256, 0, stream>>>(
      xb, wqkvb, qkv, LDQKV, cosb, sinb, qs, ks, v_t);
  // 2. causal GQA flash attention -> y (unpaired quad blocks, grid 1024)
  attn<<<dim3(1024), 512, 0, stream>>>(qkv, v_t, y);
  // 3. output projection (XCD-clustered, BK=64)
  gemm_bb<0, 8, float><<<dim3(512), 256, 0, stream>>>(
      y, wob, out, D_MODEL, nullptr, nullptr, nullptr, nullptr, nullptr);
}

// Round 25
// 135.443 us; speedup vs baseline: 1.1436x; 1.0314x over previous
//
#include <hip/hip_runtime.h>
#include <hip/hip_bf16.h>
#include <stdint.h>

typedef __attribute__((ext_vector_type(8)))  __bf16 bf16x8;
typedef __attribute__((ext_vector_type(4)))  float  f32x4;
typedef __attribute__((ext_vector_type(16))) float  f32x16;
typedef __hip_bfloat16 bf16_t;

#define T_SEQ 2048
#define D_MODEL 1024
#define N_HEADS 16
#define N_KV 4
#define HD 64
#define LDQKV 1536
#define KDIM 1024

// Convert 16 consecutive fp32 (4x float4) -> 16 bf16 (2x int4)
__device__ inline void cvt16(const float4* __restrict__ g, int4* __restrict__ s) {
  float4 v0 = g[0], v1 = g[1], v2 = g[2], v3 = g[3];
  union { int4 i[2]; __hip_bfloat162 h[8]; } u;
  u.h[0] = __float22bfloat162_rn(make_float2(v0.x, v0.y));
  u.h[1] = __float22bfloat162_rn(make_float2(v0.z, v0.w));
  u.h[2] = __float22bfloat162_rn(make_float2(v1.x, v1.y));
  u.h[3] = __float22bfloat162_rn(make_float2(v1.z, v1.w));
  u.h[4] = __float22bfloat162_rn(make_float2(v2.x, v2.y));
  u.h[5] = __float22bfloat162_rn(make_float2(v2.z, v2.w));
  u.h[6] = __float22bfloat162_rn(make_float2(v3.x, v3.y));
  u.h[7] = __float22bfloat162_rn(make_float2(v3.z, v3.w));
  s[0] = u.i[0]; s[1] = u.i[1];
}

__device__ inline void storeC(bf16_t* p, float v) { *p = __float2bfloat16(v); }
__device__ inline void storeC(float* p, float v) { *p = v; }

// v_permlane32_swap_b32 vdst, vsrc: after plswap(a,b): a={a_L,b_L}, b={a_U,b_U}
__device__ inline void plswap(unsigned& a, unsigned& b) {
  asm volatile("v_permlane32_swap_b32 %0, %1" : "+v"(a), "+v"(b));
}

// HW transcendental exp2 (input already in log2 domain)
__device__ inline float fexp2(float x) {
  float r; asm("v_exp_f32 %0, %1" : "=v"(r) : "v"(x)); return r;
}
// HW packed fp32->bf16 (T12 recipe; no builtin on gfx950)
__device__ inline unsigned cvtpk(float lo, float hi) {
  unsigned r; asm("v_cvt_pk_bf16_f32 %0, %1, %2" : "=v"(r) : "v"(lo), "v"(hi));
  return r;
}

// async global->LDS, 16B per lane; lds dest must be wave-uniform base.
__device__ inline void gll16(const bf16_t* g, bf16_t* l) {
  __builtin_amdgcn_global_load_lds(
      (const __attribute__((address_space(1))) void*)g,
      (__attribute__((address_space(3))) void*)l, 16, 0, 0);
}

// ---------------------------------------------------------------------------
// fp32 -> bf16 bulk convert, x + all weights in ONE launch (units of 16 elem)
// ---------------------------------------------------------------------------
__global__ __launch_bounds__(256) void all_cvt(
    const float* __restrict__ x,
    const float* __restrict__ Wq, const float* __restrict__ Wk,
    const float* __restrict__ Wv, const float* __restrict__ Wo,
    bf16_t* __restrict__ xb, bf16_t* __restrict__ wqkvb,
    bf16_t* __restrict__ wob) {
  const int i = blockIdx.x * 256 + threadIdx.x;
  const float* s; bf16_t* d; int off;
  if (i < 524288)      { s = x;  d = xb;                   off = i; }
  else if (i < 589824) { s = Wq; d = wqkvb;                off = i - 524288; }
  else if (i < 606208) { s = Wk; d = wqkvb + 1024 * 1024;  off = i - 589824; }
  else if (i < 622592) { s = Wv; d = wqkvb + 1280 * 1024;  off = i - 606208; }
  else                 { s = Wo; d = wob;                  off = i - 622592; }
  cvt16((const float4*)s + off * 4, (int4*)d + off * 2);
}

// ---------------------------------------------------------------------------
// GEMM bf16 x bf16, r24 structure (XCD panel clustering, fused QKV epilogue,
// BK=64) + T3 2-phase LDS double-buffer: issue next round's global_load_lds
// into buf^1 BEFORE computing buf, so L2 latency hides under the 32 MFMAs.
// One barrier per round. LDS 64KB (2 bufs x (A 8KBx2 + B 8KBx2)).
// ---------------------------------------------------------------------------
template <int MODE, int NX, typename CT>
__global__ __launch_bounds__(256) void gemm_bb(
    const bf16_t* __restrict__ A, const bf16_t* __restrict__ W,
    CT* __restrict__ C, const int ldC,
    const float* __restrict__ cosb, const float* __restrict__ sinb,
    const float* __restrict__ qs, const float* __restrict__ ks,
    bf16_t* __restrict__ v_t)
{
  __shared__ bf16_t Smem[32768];        // 64 KB: dbuf x (As0|As1|Bs0|Bs1)
  const int tid = threadIdx.x;
  const int lane = tid & 63;
  const int wv = tid >> 6;
  const int wr = wv >> 1, wc = wv & 1;
  // XCD-clustered decode: id&7 == m_panel&7 under round-robin dispatch.
  const int id  = (int)blockIdx.x;
  const int xcd = id & 7;
  const int seq = id >> 3;
  const int mp  = (seq / NX) * 8 + xcd;
  const int nt  = seq - (seq / NX) * NX;
  const int m0 = mp * 128;
  const int n0 = nt * 128;

  const int srow = lane >> 2;
  const int scol = (lane & 3) * 8;
  const bf16_t* gA = A + (size_t)(m0 + 32 * wv + srow) * KDIM + scol;
  const bf16_t* gB = W + (size_t)(n0 + 32 * wv + srow) * KDIM + scol;
  const int lOff = wv * 1024;

  f32x4 acc[4][4];
#pragma unroll
  for (int m = 0; m < 4; ++m)
#pragma unroll
    for (int n = 0; n < 4; ++n)
      acc[m][n] = {0.f, 0.f, 0.f, 0.f};

  const int fr = lane & 15;
  const int fq = lane >> 4;

#define STAGE_GEMM(bufb, kk) {                                        \
    bf16_t* _bs = Smem + (bufb) * 16384 + lOff;                       \
    gll16(gA + (kk), _bs);                                            \
    gll16(gA + 16 * KDIM + (kk), _bs + 512);                          \
    gll16(gA + (kk) + 32, _bs + 4096);                                \
    gll16(gA + 16 * KDIM + (kk) + 32, _bs + 4608);                    \
    gll16(gB + (kk), _bs + 8192);                                     \
    gll16(gB + 16 * KDIM + (kk), _bs + 8704);                         \
    gll16(gB + (kk) + 32, _bs + 12288);                               \
    gll16(gB + 16 * KDIM + (kk) + 32, _bs + 12800);                   \
  }

  STAGE_GEMM(0, 0);
  __syncthreads();

  int buf = 0;
  for (int r = 0; r < 16; ++r) {
    if (r + 1 < 16) STAGE_GEMM(buf ^ 1, (r + 1) * 64);
    const bf16_t* base = Smem + buf * 16384;
#pragma unroll
    for (int half = 0; half < 2; ++half) {
      const bf16_t* As = base + half * 4096;
      const bf16_t* Bs = base + 8192 + half * 4096;
      bf16x8 af[4], bfv[4];
#pragma unroll
      for (int m = 0; m < 4; ++m)
        af[m] = *(const bf16x8*)(&As[(wr * 64 + m * 16 + fr) * 32 + fq * 8]);
#pragma unroll
      for (int n = 0; n < 4; ++n)
        bfv[n] = *(const bf16x8*)(&Bs[(wc * 64 + n * 16 + fr) * 32 + fq * 8]);
#pragma unroll
      for (int m = 0; m < 4; ++m)
#pragma unroll
        for (int n = 0; n < 4; ++n)
          acc[m][n] = __builtin_amdgcn_mfma_f32_16x16x32_bf16(af[m], bfv[n],
                                                              acc[m][n], 0, 0, 0);
    }
    __syncthreads();
    buf ^= 1;
  }
#undef STAGE_GEMM

  if (MODE == 0 || n0 < 1280) {
    if (MODE == 1) {
      const float* stab = (n0 < 1024) ? qs : ks;
      float sc0 = stab[fr], sc1 = stab[16 + fr], sc2 = stab[32 + fr], sc3 = stab[48 + fr];
#pragma unroll
      for (int m = 0; m < 4; ++m)
#pragma unroll
        for (int r = 0; r < 4; ++r) {
          const int row = m0 + wr * 64 + m * 16 + fq * 4 + r;
          const int t = row & (T_SEQ - 1);
          float ss = acc[m][0][r] * acc[m][0][r] + acc[m][1][r] * acc[m][1][r]
                   + acc[m][2][r] * acc[m][2][r] + acc[m][3][r] * acc[m][3][r];
          ss += __shfl_xor(ss, 1);
          ss += __shfl_xor(ss, 2);
          ss += __shfl_xor(ss, 4);
          ss += __shfl_xor(ss, 8);
          const float nrm = rsqrtf(ss * (1.f / 64.f) + 1e-6f);
          const float v0 = acc[m][0][r] * nrm * sc0;
          const float v1 = acc[m][1][r] * nrm * sc1;
          const float v2 = acc[m][2][r] * nrm * sc2;
          const float v3 = acc[m][3][r] * nrm * sc3;
          const float c = cosb[t * 16 + fr];
          const float s = sinb[t * 16 + fr];
          union { unsigned u; bf16_t hh[2]; } pa, pb;
          pa.u = cvtpk(v0 * c - v1 * s, v0 * s + v1 * c);
          pb.u = cvtpk(v2, v3);
          bf16_t* p = (bf16_t*)C + (size_t)row * ldC + n0 + wc * 64 + fr;
          p[0]  = pa.hh[0];
          p[16] = pa.hh[1];
          p[32] = pb.hh[0];
          p[48] = pb.hh[1];
        }
    } else {
#pragma unroll
      for (int m = 0; m < 4; ++m)
#pragma unroll
        for (int n = 0; n < 4; ++n)
#pragma unroll
          for (int r = 0; r < 4; ++r) {
            const int row = wr * 64 + m * 16 + fq * 4 + r;
            const int col = wc * 64 + n * 16 + fr;
            storeC(&C[(size_t)(m0 + row) * ldC + n0 + col], acc[m][n][r]);
          }
    }
  } else {
    // v blocks: coalesced transposed store via LDS (r22-proven).
    const int b4 = (m0 >> 11) * 4;
    const int t0base = m0 & (T_SEQ - 1);
    const int vcol = tid & 127;
    const int vc = n0 - 1280 + vcol;
    const int g = b4 + (vc >> 6);
    const int d = vc & 63;
#pragma unroll
    for (int half = 0; half < 2; ++half) {
      if (wr == half) {
#pragma unroll
        for (int m = 0; m < 4; ++m)
#pragma unroll
          for (int n = 0; n < 4; ++n)
#pragma unroll
            for (int r2 = 0; r2 < 4; r2 += 2) {
              union { unsigned u; bf16_t hh[2]; } pk2;
              pk2.u = cvtpk(acc[m][n][r2], acc[m][n][r2 + 1]);
              const int tl0 = m * 16 + fq * 4 + r2;
              const int col = wc * 64 + n * 16 + fr;
              const int sw = ((tl0 >> 2) & 7) << 4;   // same for tl0, tl0+1
              Smem[tl0 * 128 + (col ^ sw)]       = pk2.hh[0];
              Smem[(tl0 + 1) * 128 + (col ^ sw)] = pk2.hh[1];
            }
      }
      __syncthreads();
      bf16_t* dst0 = v_t + ((size_t)(g * HD + d)) * T_SEQ + t0base + half * 64;
#pragma unroll
      for (int ci = 0; ci < 2; ++ci) {
        const int cu = (tid >> 7) + ci * 2;           // chunk 0..3 (16 t each)
        union { int4 q[2]; bf16_t hh[16]; } ld;
#pragma unroll
        for (int t = 0; t < 16; ++t) {
          const int tt = cu * 16 + t;
          ld.hh[t] = Smem[tt * 128 + (vcol ^ (((tt >> 2) & 7) << 4))];
        }
        *(int4*)(dst0 + cu * 16)     = ld.q[0];
        *(int4*)(dst0 + cu * 16 + 8) = ld.q[1];
      }
      __syncthreads();
    }
  }
}

// ---------------------------------------------------------------------------
// Causal GQA flash attention v16 (unchanged from r21 — passing): unpaired
// strips, quad blocks, split-k-2, balanced permutation, grid 1024.
// ---------------------------------------------------------------------------
__global__ __launch_bounds__(512) void attn(
    const bf16_t* __restrict__ qkv, const bf16_t* __restrict__ v_t,
    bf16_t* __restrict__ y)
{
  __shared__ int4 lds[2048];      // 32 KB: dbuf x (K 8KB + V 8KB)
  const int tid  = threadIdx.x;   // 0..511
  const int lane = tid & 63;
  const int w    = tid >> 6;      // 0..7
  const int spair= w >> 1;        // 0..3: strip within quad
  const int h    = w & 1;         // split-k parity
  const int ql   = lane & 31;
  const int hi   = lane >> 5;
  const int id   = (int)blockIdx.x;          // 0..1023
  const int low3 = id & 7;
  const int rest = id >> 3;                  // 0..127
  const int gsel = rest & 1;
  const int hh   = (rest >> 1) & 3;
  const int sbi  = rest >> 3;                // 0..15: quad index (pre-perm)
  const int sb   = ((sbi >> 2) & 1) ? (sbi + 4 - ((sbi >> 3) << 4)) : (15 - sbi);
  const int g16  = low3 + 8 * gsel;          // b*4+kvh (same-XCD clustering)
  const int b    = g16 >> 2, kvh = g16 & 3;
  const int hd   = kvh * 4 + hh;
  const int s    = 4 * sb + spair;           // this wave's single strip
  const int q_glob = s * 32 + ql;
  const int nt   = s + 1;                    // strip's 32-k tiles
  const int nR   = 2 * sb + 2;               // block-uniform 64-k rounds
  const float SCALE_LOG2 = 0.125f * 1.44269504089f;

  const int sid = tid & 255;
  const int u   = tid >> 8;
  const int kr = sid >> 3, kslot = sid & 7;
  const int vd = sid >> 2, vslot = sid & 3;
  const bf16_t* gK = qkv + (size_t)(b * T_SEQ + kr + u * 32) * LDQKV + 1024 + kvh * HD + kslot * 8;
  const bf16_t* gV = v_t + (size_t)((b * N_KV + kvh) * HD + vd) * T_SEQ + vslot * 8 + u * 32;
  const int wKidx = u * 256 + kr * 8 + (kslot ^ (kr & 7));
  const int wVidx = 512 + u * 256 + vd * 4 + (vslot ^ ((vd >> 1) & 3));

  int kridx[4];
#pragma unroll
  for (int c = 0; c < 4; ++c)
    kridx[c] = ql * 8 + ((2 * c + hi) ^ (ql & 7));
  const int vsw = (ql >> 1) & 3;
  const int v0idx = 512 + ql * 4 + (hi ^ vsw);
  const int v1idx = 512 + ql * 4 + ((2 + hi) ^ vsw);
  const int v2idx = 512 + (ql + 32) * 4 + (hi ^ vsw);
  const int v3idx = 512 + (ql + 32) * 4 + ((2 + hi) ^ vsw);

  union ob { unsigned uu[4]; bf16x8 v; } onesf;
#pragma unroll
  for (int i = 0; i < 4; ++i) onesf.uu[i] = 0x3F803F80u;

  f32x16 zro;
#pragma unroll
  for (int i = 0; i < 16; ++i) zro[i] = 0.f;

  float* lf = (float*)lds;

  const bf16_t* Qrow = qkv + (size_t)(b * T_SEQ + q_glob) * LDQKV + hd * HD + hi * 8;
  bf16x8 qfrag[4];
#pragma unroll
  for (int c = 0; c < 4; ++c) {
    bf16x8 raw = *(const bf16x8*)(Qrow + c * 16);
    bf16x8 sc;
#pragma unroll
    for (int j = 0; j < 8; ++j)
      sc[j] = (__bf16)((float)raw[j] * SCALE_LOG2);
    qfrag[c] = sc;
  }

  f32x16 acc0, acc1, accL;
#pragma unroll
  for (int i = 0; i < 16; ++i) { acc0[i] = 0.f; acc1[i] = 0.f; accL[i] = 0.f; }
  float m_run = -1e30f;

  {
    int4 kA = *(const int4*)gK;
    int4 vA = *(const int4*)gV;
    lds[wKidx] = kA;
    lds[wVidx] = vA;
  }
  __syncthreads();

  int buf = 0;
  for (int r = 0; r < nR; ++r) {
    int4 kA, vA;
    const bool more = (r + 1 < nR);
    if (more) {
      kA = *(const int4*)(gK + (size_t)(r + 1) * 64 * LDQKV);
      vA = *(const int4*)(gV + (r + 1) * 64);
    }

    const int t = 2 * r + h;     // this wave's tile (parity split)
    if (t < nt) {
      const int k0 = t << 5;
      const bool masked = (t == nt - 1);
      const int base = buf * 1024 + h * 256;

      bf16x8 kf0 = *(const bf16x8*)&lds[base + kridx[0]];
      bf16x8 kf1 = *(const bf16x8*)&lds[base + kridx[1]];
      bf16x8 kf2 = *(const bf16x8*)&lds[base + kridx[2]];
      bf16x8 kf3 = *(const bf16x8*)&lds[base + kridx[3]];

      __builtin_amdgcn_s_setprio(1);
      f32x16 st = __builtin_amdgcn_mfma_f32_32x32x16_bf16(kf0, qfrag[0], zro, 0, 0, 0);
      st = __builtin_amdgcn_mfma_f32_32x32x16_bf16(kf1, qfrag[1], st, 0, 0, 0);
      st = __builtin_amdgcn_mfma_f32_32x32x16_bf16(kf2, qfrag[2], st, 0, 0, 0);
      st = __builtin_amdgcn_mfma_f32_32x32x16_bf16(kf3, qfrag[3], st, 0, 0, 0);
      __builtin_amdgcn_s_setprio(0);

      if (masked) {
#pragma unroll
        for (int rr = 0; rr < 16; ++rr) {
          const int kg = k0 + (rr & 3) + 8 * (rr >> 2) + 4 * hi;
          if (kg > q_glob) st[rr] = -1e30f;
        }
      }
      float m01 = fmaxf(fmaxf(st[0], st[1]), st[2]);
      float m02 = fmaxf(fmaxf(st[3], st[4]), st[5]);
      float m03 = fmaxf(fmaxf(st[6], st[7]), st[8]);
      float m04 = fmaxf(fmaxf(st[9], st[10]), st[11]);
      float m05 = fmaxf(fmaxf(st[12], st[13]), st[14]);
      float m06 = fmaxf(fmaxf(m01, m02), m03);
      float m07 = fmaxf(fmaxf(m04, m05), st[15]);
      const float bmax = fmaxf(m06, m07);
      if (__any(bmax > m_run + 8.f)) {        // T13 defer-max
        const float rmax = fmaxf(bmax, __shfl_xor(bmax, 32));
        const float mnew = fmaxf(m_run, rmax);
        const float corr = fexp2(m_run - mnew);
#pragma unroll
        for (int i = 0; i < 16; ++i) { acc0[i] *= corr; acc1[i] *= corr; }
        accL[0] *= corr;
        m_run = mnew;
      }
      float pp[16];
#pragma unroll
      for (int rr = 0; rr < 16; ++rr) pp[rr] = fexp2(st[rr] - m_run);

      unsigned wp[8];
#pragma unroll
      for (int i = 0; i < 8; ++i) wp[i] = cvtpk(pp[2 * i], pp[2 * i + 1]);
      plswap(wp[0], wp[2]); plswap(wp[1], wp[3]);
      plswap(wp[4], wp[6]); plswap(wp[5], wp[7]);
      union fu { unsigned uu2[4]; bf16x8 v; };
      fu f1, f2;
      f1.uu2[0] = wp[0]; f1.uu2[1] = wp[1]; f1.uu2[2] = wp[2]; f1.uu2[3] = wp[3];
      f2.uu2[0] = wp[4]; f2.uu2[1] = wp[5]; f2.uu2[2] = wp[6]; f2.uu2[3] = wp[7];

      bf16x8 vf0 = *(const bf16x8*)&lds[base + v0idx];
      bf16x8 vf1 = *(const bf16x8*)&lds[base + v1idx];
      bf16x8 vf2 = *(const bf16x8*)&lds[base + v2idx];
      bf16x8 vf3 = *(const bf16x8*)&lds[base + v3idx];

      __builtin_amdgcn_s_setprio(1);
      acc0 = __builtin_amdgcn_mfma_f32_32x32x16_bf16(vf0, f1.v, acc0, 0, 0, 0);
      acc0 = __builtin_amdgcn_mfma_f32_32x32x16_bf16(vf1, f2.v, acc0, 0, 0, 0);
      acc1 = __builtin_amdgcn_mfma_f32_32x32x16_bf16(vf2, f1.v, acc1, 0, 0, 0);
      acc1 = __builtin_amdgcn_mfma_f32_32x32x16_bf16(vf3, f2.v, acc1, 0, 0, 0);
      accL = __builtin_amdgcn_mfma_f32_32x32x16_bf16(onesf.v, f1.v, accL, 0, 0, 0);
      accL = __builtin_amdgcn_mfma_f32_32x32x16_bf16(onesf.v, f2.v, accL, 0, 0, 0);
      __builtin_amdgcn_s_setprio(0);
    }

    if (more) {
      const int nb = (buf ^ 1) * 1024;
      lds[nb + wKidx] = kA;
      lds[nb + wVidx] = vA;
    }
    __syncthreads();
    buf ^= 1;
  }

  // ---- split-k merge: h=1 publishes partials, h=0 merges & stores ----
  float cA = 1.f, cB = 0.f, l_mrg = 0.f;
  if (h == 1) {
    const int fb = spair * 1216 + lane * 19;
#pragma unroll
    for (int i = 0; i < 16; ++i) lf[fb + i] = acc0[i];
    lf[fb + 16] = m_run;
    lf[fb + 17] = accL[0];
  }
  __syncthreads();
  if (h == 0) {
    const int fb = spair * 1216 + lane * 19;
    const float mB = lf[fb + 16], lB = lf[fb + 17];
    const float mM = fmaxf(m_run, mB);
    cA = fexp2(m_run - mM);
    cB = fexp2(mB - mM);
    l_mrg = accL[0] * cA + lB * cB;
#pragma unroll
    for (int i = 0; i < 16; ++i) acc0[i] = acc0[i] * cA + lf[fb + i] * cB;
  }
  __syncthreads();
  if (h == 1) {
    const int fb2 = spair * 1088 + lane * 17;
#pragma unroll
    for (int i = 0; i < 16; ++i) lf[fb2 + i] = acc1[i];
  }
  __syncthreads();
  if (h == 0) {
    const int fb2 = spair * 1088 + lane * 17;
#pragma unroll
    for (int i = 0; i < 16; ++i) acc1[i] = acc1[i] * cA + lf[fb2 + i] * cB;
    const float inv = 1.f / l_mrg;
    bf16_t* yrow = y + (size_t)(b * T_SEQ + q_glob) * D_MODEL + hd * HD;
#pragma unroll
    for (int gg = 0; gg < 4; ++gg) {
      uint2 o0, o1;
      o0.x = cvtpk(acc0[4 * gg + 0] * inv, acc0[4 * gg + 1] * inv);
      o0.y = cvtpk(acc0[4 * gg + 2] * inv, acc0[4 * gg + 3] * inv);
      o1.x = cvtpk(acc1[4 * gg + 0] * inv, acc1[4 * gg + 1] * inv);
      o1.y = cvtpk(acc1[4 * gg + 2] * inv, acc1[4 * gg + 3] * inv);
      *(uint2*)(yrow + 8 * gg + 4 * hi)      = o0;
      *(uint2*)(yrow + 32 + 8 * gg + 4 * hi) = o1;
    }
  }
}

// ---------------------------------------------------------------------------
extern "C" void kernel_launch(void* const* d_in, const int* in_sizes, int n_in,
                              void* d_out, int out_size, void* d_ws,
                              size_t ws_size, hipStream_t stream) {
  const float* x    = (const float*)d_in[0];
  const float* cosb = (const float*)d_in[1];
  const float* sinb = (const float*)d_in[2];
  const float* Wq   = (const float*)d_in[3];
  const float* Wk   = (const float*)d_in[4];
  const float* Wv   = (const float*)d_in[5];
  const float* Wo   = (const float*)d_in[6];
  const float* qs   = (const float*)d_in[7];
  const float* ks   = (const float*)d_in[8];
  float* out = (float*)d_out;   // reference output dtype is float32

  char* ws = (char*)d_ws;
  bf16_t* qkv   = (bf16_t*)ws;                       // 25165824 B
  bf16_t* v_t   = (bf16_t*)(ws + 25165824);          // 4194304 B
  bf16_t* y     = (bf16_t*)(ws + 29360128);          // 16777216 B (= xb alias)
  bf16_t* xb    = y;                                 // xb dead before attn writes y
  bf16_t* wqkvb = (bf16_t*)(ws + 46137344);          // 3145728 B
  bf16_t* wob   = (bf16_t*)(ws + 49283072);          // 2097152 B

  // 0. fp32 -> bf16 converts (one launch: x + all weights)
  all_cvt<<<dim3(2688), 256, 0, stream>>>(x, Wq, Wk, Wv, Wo, xb, wqkvb, wob);

  // 1. fused QKV projection + RMSNorm + RoPE + V-transpose (XCD-clustered,
  //    BK=64, 2-phase dbuf)
  gemm_bb<1, 12, bf16_t><<<dim3(768), 256, 0, stream>>>(
      xb, wqkvb, qkv, LDQKV, cosb, sinb, qs, ks, v_t);
  // 2. causal GQA flash attention -> y (unpaired quad blocks, grid 1024)
  attn<<<dim3(1024), 512, 0, stream>>>(qkv, v_t, y);
  // 3. output projection (XCD-clustered, BK=64, 2-phase dbuf)
  gemm_bb<0, 8, float><<<dim3(512), 256, 0, stream>>>(
      y, wob, out, D_MODEL, nullptr, nullptr, nullptr, nullptr, nullptr);
}